// Round 6
// baseline (5102.541 us; speedup 1.0000x reference)
//
#include <hip/hip_runtime.h>
#include <math.h>

#define Bq    1024
#define Nn    29
#define DIMq  64
#define Kq    8
#define MD    16
#define EIN   129
#define EH    258   // 2*EIN
#define CHID  64    // 4*MD
#define NIN   80    // DIM+MD
#define NHID  128   // 2*DIM
#define DEPTHq 4
#define NPASS 3
#define PCOLS 86    // columns per c-pass (3*86 = 258)
#define PQS   92    // P/Q LDS row stride (92%32=28 -> j-gather bank spread)
#define FS    68    // s_f row stride
#define UPQN  6032  // max(2*29*92=5336, ni 2320 + nh 3712 = 6032); partials live at +2320

__device__ __forceinline__ float silu_f(float x) {
    float e = __expf(-x);
    return x * __builtin_amdgcn_rcpf(1.0f + e);
}

__global__ void k_init(const int* __restrict__ tokens,
                       const float* __restrict__ temb,
                       const float* __restrict__ pemb,
                       float* __restrict__ feats) {
    int o = blockIdx.x * 256 + threadIdx.x;
    if (o >= Bq * Nn * DIMq) return;
    int d = o & (DIMq - 1);
    int bn = o >> 6;
    int n = bn % Nn;
    int t = tokens[bn];
    feats[o] = temb[t * DIMq + d] + pemb[n * DIMq + d];
}

__global__ __launch_bounds__(512, 8)
void k_layer(const float* __restrict__ feats_in, const float* __restrict__ coors_in,
             float* __restrict__ feats_out, float* __restrict__ coors_out,
             const float* __restrict__ ew1, const float* __restrict__ eb1,
             const float* __restrict__ ew2, const float* __restrict__ eb2,
             const float* __restrict__ cw1, const float* __restrict__ cb1,
             const float* __restrict__ cw2, const float* __restrict__ cb2,
             const float* __restrict__ csc,
             const float* __restrict__ lng, const float* __restrict__ lnb,
             const float* __restrict__ nw1, const float* __restrict__ nb1,
             const float* __restrict__ nw2, const float* __restrict__ nb2,
             int layer) {
    ew1 += (size_t)layer * EIN * EH;   eb1 += layer * EH;
    ew2 += (size_t)layer * EH * MD;    eb2 += layer * MD;
    cw1 += (size_t)layer * MD * CHID;  cb1 += layer * CHID;
    cw2 += layer * CHID;               cb2 += layer;
    lng += layer * DIMq;               lnb += layer * DIMq;
    nw1 += (size_t)layer * NIN * NHID; nb1 += layer * NHID;
    nw2 += (size_t)layer * NHID * DIMq; nb2 += layer * DIMq;
    const float cscale = csc[layer];

    __shared__ float uPQ[UPQN];            // P rows [0..28], Q rows [29..57] per pass; later ni/nh
    __shared__ float s_f[Nn][FS];
    __shared__ float s_c[Nn][3];
    __shared__ int   s_idx[Nn][Kq];
    __shared__ float s_dk[Nn][Kq];
    __shared__ union RegB {                // d2 dead after kNN -> cw/mi
        float d2[Nn][Nn];
        struct { float cw[232]; float mi[Nn][MD]; } e;
    } ub;
    float* s_ni   = uPQ;                   // [Nn][NIN]
    float* s_nh   = uPQ + Nn * NIN;        // [Nn][NHID]
    float* s_part = uPQ + Nn * NIN;        // [232][MD] m-partials (PQ dead by then)

    const int b = blockIdx.x;
    const int tid = threadIdx.x;
    const int half = tid >> 8;             // wave-group half (wave-uniform)
    const int eh = tid & 255;

    // ---- stage feats + coords ----
    const float* fb = feats_in + (size_t)b * Nn * DIMq;
    for (int o = tid; o < Nn * DIMq; o += 512) s_f[o >> 6][o & 63] = fb[o];
    if (tid < Nn * 3) s_c[0][tid] = coors_in[(size_t)b * Nn * 3 + tid];
    __syncthreads();

    // ---- all-pairs squared distances (exact rounding: kNN-critical) ----
    for (int o = tid; o < Nn * Nn; o += 512) {
        int i = o / Nn, j = o % Nn;
        float dx = __fsub_rn(s_c[i][0], s_c[j][0]);
        float dy = __fsub_rn(s_c[i][1], s_c[j][1]);
        float dz = __fsub_rn(s_c[i][2], s_c[j][2]);
        ub.d2[i][j] = __fadd_rn(__fadd_rn(__fmul_rn(dx, dx), __fmul_rn(dy, dy)),
                                __fmul_rn(dz, dz));
    }
    __syncthreads();

    // ---- parallel stable K-nearest: 8 lanes per node (tie: dist2, then index) ----
    if (tid < Nn * Kq) {
        const int g = tid >> 3, l = tid & 7;
        unsigned chosen = 0;
        for (int r = 0; r < Kq; ++r) {
            float bv = 3.4e38f; int bj = 64;
            for (int j = l; j < Nn; j += 8) {
                if ((chosen >> j) & 1u) continue;
                float v = ub.d2[g][j];
                if (v < bv) { bv = v; bj = j; }
            }
            #pragma unroll
            for (int off = 1; off < 8; off <<= 1) {
                float ov = __shfl_xor(bv, off);
                int   oj = __shfl_xor(bj, off);
                if (ov < bv || (ov == bv && oj < bj)) { bv = ov; bj = oj; }
            }
            chosen |= 1u << bj;
            if (l == 0) { s_idx[g][r] = bj; s_dk[g][r] = bv; }
        }
    }
    __syncthreads();

    // ---- edge state: both halves cover all 232 edges, split by c-range ----
    const int e   = (eh < 232) ? eh : 231;
    const int n_e = e >> 3;
    const int k_e = e & 7;
    const int jj  = s_idx[n_e][k_e];
    const float dd = s_dk[n_e][k_e];
    float m[MD];
    #pragma unroll
    for (int q = 0; q < MD; ++q) m[q] = 0.f;

#define ACC_COL(Pv, Qv, CG) do {                                  \
        float pre = (Pv) + (Qv) + dd * wdrow[CG];                 \
        float h = silu_f(pre);                                    \
        const float* w2r = ew2 + (size_t)(CG) * MD;               \
        _Pragma("unroll")                                         \
        for (int q = 0; q < MD; ++q) m[q] = fmaf(h, w2r[q], m[q]);\
    } while (0)

    // ---- three c-passes: P/Q panels -> per-edge streamed accumulation ----
    for (int pass = 0; pass < NPASS; ++pass) {
        const int c0 = pass * PCOLS;

        // P/Q: 344 tasks = 86 cols x {P,Q} x {rows 0-14, 15-28}
        if (tid < 4 * PCOLS) {
            const int cl = tid >> 2, r = tid & 3;
            const bool isP = r < 2;
            const bool full15 = (r & 1) == 0;
            const int n0 = (r & 1) * 15;
            const int cg = c0 + cl;
            const float* wcol = ew1 + (isP ? 0 : 64) * EH + cg;
            float init = isP ? eb1[cg] : 0.f;
            float acc[15];
            #pragma unroll
            for (int u = 0; u < 15; ++u) acc[u] = init;
            #pragma unroll 2
            for (int ig = 0; ig < 16; ++ig) {
                float w0 = wcol[(4 * ig + 0) * EH], w1 = wcol[(4 * ig + 1) * EH];
                float w2v = wcol[(4 * ig + 2) * EH], w3 = wcol[(4 * ig + 3) * EH];
                #pragma unroll
                for (int u = 0; u < 14; ++u) {
                    float4 f4 = *(const float4*)&s_f[n0 + u][4 * ig];
                    acc[u] = fmaf(f4.x, w0, acc[u]);
                    acc[u] = fmaf(f4.y, w1, acc[u]);
                    acc[u] = fmaf(f4.z, w2v, acc[u]);
                    acc[u] = fmaf(f4.w, w3, acc[u]);
                }
                if (full15) {
                    float4 f4 = *(const float4*)&s_f[14][4 * ig];
                    acc[14] = fmaf(f4.x, w0, acc[14]);
                    acc[14] = fmaf(f4.y, w1, acc[14]);
                    acc[14] = fmaf(f4.z, w2v, acc[14]);
                    acc[14] = fmaf(f4.w, w3, acc[14]);
                }
            }
            const int rbase = (isP ? 0 : Nn) + n0;
            #pragma unroll
            for (int u = 0; u < 14; ++u) uPQ[(rbase + u) * PQS + cl] = acc[u];
            if (full15) uPQ[(rbase + 14) * PQS + cl] = acc[14];
        }
        __syncthreads();

        // edge accumulation: half0 -> quads [0,44), half1 -> [44,84) + cols 84,85
        {
            const float* Prow = uPQ + n_e * PQS;
            const float* Qrow = uPQ + (Nn + jj) * PQS;
            const float* wdrow = ew1 + 128 * EH;
            const int cb = half ? 44 : 0;
            const int nq = half ? 10 : 11;
            for (int t = 0; t < nq; ++t) {
                const int cl = cb + 4 * t;
                float4 P4 = *(const float4*)(Prow + cl);
                float4 Q4 = *(const float4*)(Qrow + cl);
                const int cg = c0 + cl;
                ACC_COL(P4.x, Q4.x, cg);
                ACC_COL(P4.y, Q4.y, cg + 1);
                ACC_COL(P4.z, Q4.z, cg + 2);
                ACC_COL(P4.w, Q4.w, cg + 3);
            }
            if (half) {
                ACC_COL(Prow[84], Qrow[84], c0 + 84);
                ACC_COL(Prow[85], Qrow[85], c0 + 85);
            }
        }
        __syncthreads();
    }
#undef ACC_COL

    // ---- m-combine via LDS (PQ panels now dead) ----
    if (half == 1 && eh < 232) {
        float4* pp = (float4*)(s_part + e * MD);
        pp[0] = make_float4(m[0], m[1], m[2], m[3]);
        pp[1] = make_float4(m[4], m[5], m[6], m[7]);
        pp[2] = make_float4(m[8], m[9], m[10], m[11]);
        pp[3] = make_float4(m[12], m[13], m[14], m[15]);
    }
    __syncthreads();

    if (half == 0) {
        // finish edges: combine, silu, coor MLP, cw + mi pool
        const float4* pp = (const float4*)(s_part + e * MD);
        float4 p0 = pp[0], p1 = pp[1], p2 = pp[2], p3 = pp[3];
        m[0] += p0.x; m[1] += p0.y; m[2]  += p0.z; m[3]  += p0.w;
        m[4] += p1.x; m[5] += p1.y; m[6]  += p1.z; m[7]  += p1.w;
        m[8] += p2.x; m[9] += p2.y; m[10] += p2.z; m[11] += p2.w;
        m[12] += p3.x; m[13] += p3.y; m[14] += p3.z; m[15] += p3.w;
        #pragma unroll
        for (int q = 0; q < MD; ++q) m[q] = silu_f(eb2[q] + m[q]);

        float cwacc = cb2[0];
        #pragma unroll
        for (int ch = 0; ch < 4; ++ch) {
            float hh[16];
            const float* cb1c = cb1 + 16 * ch;
            #pragma unroll
            for (int q = 0; q < 16; ++q) hh[q] = cb1c[q];
            #pragma unroll
            for (int i = 0; i < MD; ++i) {
                const float* wr = cw1 + i * CHID + 16 * ch;   // uniform -> s_load
                #pragma unroll
                for (int q = 0; q < 16; ++q) hh[q] = fmaf(m[i], wr[q], hh[q]);
            }
            const float* cw2c = cw2 + 16 * ch;
            #pragma unroll
            for (int q = 0; q < 16; ++q) cwacc = fmaf(silu_f(hh[q]), cw2c[q], cwacc);
        }
        cwacc = fminf(fmaxf(cwacc, -2.f), 2.f);
        if (eh < 232) ub.e.cw[e] = cwacc;

        #pragma unroll
        for (int q = 0; q < MD; ++q) {
            float v = m[q];
            v += __shfl_xor(v, 1);
            v += __shfl_xor(v, 2);
            v += __shfl_xor(v, 4);
            if (k_e == 0 && eh < 232) ub.e.mi[n_e][q] = v;
        }
    } else if (eh < Nn * Kq) {
        // concurrent LayerNorm on half1 (PQ区 [0,2320) now reusable as ni)
        const int g = eh >> 3, l = eh & 7;
        const float* fr = s_f[g];
        float4 a = *(const float4*)&fr[8 * l];
        float4 b4 = *(const float4*)&fr[8 * l + 4];
        float ps = ((a.x + a.y) + (a.z + a.w)) + ((b4.x + b4.y) + (b4.z + b4.w));
        ps += __shfl_xor(ps, 1); ps += __shfl_xor(ps, 2); ps += __shfl_xor(ps, 4);
        float mu = ps * (1.0f / 64.0f);
        float t0, pv = 0.f;
        t0 = a.x - mu;  pv = fmaf(t0, t0, pv);  t0 = a.y - mu;  pv = fmaf(t0, t0, pv);
        t0 = a.z - mu;  pv = fmaf(t0, t0, pv);  t0 = a.w - mu;  pv = fmaf(t0, t0, pv);
        t0 = b4.x - mu; pv = fmaf(t0, t0, pv);  t0 = b4.y - mu; pv = fmaf(t0, t0, pv);
        t0 = b4.z - mu; pv = fmaf(t0, t0, pv);  t0 = b4.w - mu; pv = fmaf(t0, t0, pv);
        pv += __shfl_xor(pv, 1); pv += __shfl_xor(pv, 2); pv += __shfl_xor(pv, 4);
        float rs = rsqrtf(pv * (1.0f / 64.0f) + 1e-5f);
        #pragma unroll
        for (int u = 0; u < 8; ++u) {
            int d = 8 * l + u;
            s_ni[g * NIN + d] = (fr[d] - mu) * rs * lng[d] + lnb[d];
        }
    }
    __syncthreads();

    // ---- mi copy (lanes 0..447 + wrap) and coords update (wave 7) ----
    if (tid < 448) {
        s_ni[(tid >> 4) * NIN + DIMq + (tid & 15)] = ub.e.mi[tid >> 4][tid & 15];
        if (tid < 16) s_ni[28 * NIN + DIMq + tid] = ub.e.mi[28][tid];
    } else {
        for (int t2 = tid - 448; t2 < Nn * 3; t2 += 64) {
            int n2 = t2 / 3, cix = t2 % 3;
            float acc2 = 0.f;
            for (int k2 = 0; k2 < Kq; ++k2) {
                int j2 = s_idx[n2][k2];
                float nrm = sqrtf(s_dk[n2][k2]);
                float rel = __fsub_rn(s_c[n2][cix], s_c[j2][cix]);
                float rn = rel / fmaxf(nrm, 1e-8f) * cscale;
                acc2 = fmaf(ub.e.cw[n2 * Kq + k2], rn, acc2);
            }
            coors_out[((size_t)b * Nn + n2) * 3 + cix] = s_c[n2][cix] + acc2;
        }
    }
    __syncthreads();

    // ---- node MLP hidden ----
    for (int o = tid; o < Nn * NHID; o += 512) {
        int n2 = o >> 7, c = o & 127;
        float acc = nb1[c];
        const float* nir = s_ni + n2 * NIN;
        const float* w = nw1 + c;
        #pragma unroll 4
        for (int ig = 0; ig < 20; ++ig) {
            float4 f4 = *(const float4*)(nir + 4 * ig);
            acc = fmaf(f4.x, w[(4 * ig + 0) * NHID], acc);
            acc = fmaf(f4.y, w[(4 * ig + 1) * NHID], acc);
            acc = fmaf(f4.z, w[(4 * ig + 2) * NHID], acc);
            acc = fmaf(f4.w, w[(4 * ig + 3) * NHID], acc);
        }
        s_nh[n2 * NHID + c] = silu_f(acc);
    }
    __syncthreads();

    // ---- node MLP out + residual ----
    for (int o = tid; o < Nn * DIMq; o += 512) {
        int n2 = o >> 6, c = o & 63;
        float acc = nb2[c];
        const float* nhr = s_nh + n2 * NHID;
        const float* w = nw2 + c;
        #pragma unroll 4
        for (int ig = 0; ig < 32; ++ig) {
            float4 f4 = *(const float4*)(nhr + 4 * ig);
            acc = fmaf(f4.x, w[(4 * ig + 0) * DIMq], acc);
            acc = fmaf(f4.y, w[(4 * ig + 1) * DIMq], acc);
            acc = fmaf(f4.z, w[(4 * ig + 2) * DIMq], acc);
            acc = fmaf(f4.w, w[(4 * ig + 3) * DIMq], acc);
        }
        feats_out[((size_t)b * Nn + n2) * DIMq + c] = acc + s_f[n2][c];
    }
}

__global__ __launch_bounds__(64)
void k_read(const float* __restrict__ feats,
            const float* __restrict__ rw1, const float* __restrict__ rb1,
            const float* __restrict__ rw2, const float* __restrict__ rb2,
            float* __restrict__ out) {
    __shared__ float s_mol[DIMq];
    const int b = blockIdx.x, t = threadIdx.x;
    float acc = 0.f;
    for (int n = 0; n < Nn; ++n) acc += feats[((size_t)b * Nn + n) * DIMq + t];
    s_mol[t] = acc / 29.0f;
    __syncthreads();
    float a2 = rb1[t];
    for (int i = 0; i < DIMq; ++i) a2 = fmaf(s_mol[i], rw1[i * DIMq + t], a2);
    float part = silu_f(a2) * rw2[t];
    #pragma unroll
    for (int off = 32; off > 0; off >>= 1) part += __shfl_down(part, off);
    if (t == 0) out[b] = part + rb2[0];
}

extern "C" void kernel_launch(void* const* d_in, const int* in_sizes, int n_in,
                              void* d_out, int out_size, void* d_ws, size_t ws_size,
                              hipStream_t stream) {
    const int*   tokens = (const int*)d_in[0];
    const float* coords = (const float*)d_in[1];
    // d_in[2] = mask : all-True in this problem
    const float* temb = (const float*)d_in[3];
    const float* pemb = (const float*)d_in[4];
    const float* ew1 = (const float*)d_in[5];
    const float* eb1 = (const float*)d_in[6];
    const float* ew2 = (const float*)d_in[7];
    const float* eb2 = (const float*)d_in[8];
    const float* cw1 = (const float*)d_in[9];
    const float* cb1 = (const float*)d_in[10];
    const float* cw2 = (const float*)d_in[11];
    const float* cb2 = (const float*)d_in[12];
    const float* csc = (const float*)d_in[13];
    const float* lng = (const float*)d_in[14];
    const float* lnb = (const float*)d_in[15];
    const float* nw1 = (const float*)d_in[16];
    const float* nb1 = (const float*)d_in[17];
    const float* nw2 = (const float*)d_in[18];
    const float* nb2 = (const float*)d_in[19];
    const float* rw1 = (const float*)d_in[20];
    const float* rb1 = (const float*)d_in[21];
    const float* rw2 = (const float*)d_in[22];
    const float* rb2 = (const float*)d_in[23];

    float* fA = (float*)d_ws;
    float* fB = fA + (size_t)Bq * Nn * DIMq;
    float* cA = fB + (size_t)Bq * Nn * DIMq;
    float* cB = cA + (size_t)Bq * Nn * 3;

    k_init<<<(Bq * Nn * DIMq + 255) / 256, 256, 0, stream>>>(tokens, temb, pemb, fA);

    const float* fin = fA;
    const float* cin = coords;
    float* fbufs[2] = {fB, fA};
    float* cbufs[2] = {cA, cB};
    for (int l = 0; l < DEPTHq; ++l) {
        float* fout = fbufs[l & 1];
        float* cout = cbufs[l & 1];
        k_layer<<<Bq, 512, 0, stream>>>(fin, cin, fout, cout,
                                        ew1, eb1, ew2, eb2,
                                        cw1, cb1, cw2, cb2, csc,
                                        lng, lnb, nw1, nb1, nw2, nb2, l);
        fin = fout;
        cin = cout;
    }

    k_read<<<Bq, 64, 0, stream>>>(fin, rw1, rb1, rw2, rb2, (float*)d_out);
}

// Round 7
// 1039.422 us; speedup vs baseline: 4.9090x; 4.9090x over previous
//
#include <hip/hip_runtime.h>
#include <math.h>

#define Bq    1024
#define Nn    29
#define DIMq  64
#define Kq    8
#define MD    16
#define EIN   129
#define EH    258   // 2*EIN
#define CHID  64    // 4*MD
#define NIN   80    // DIM+MD
#define NHID  128   // 2*DIM
#define DEPTHq 4
#define NPASS 3
#define PCOLS 86    // columns per c-pass (3*86 = 258)
#define PQS   92    // P/Q LDS row stride (92%32=28 -> j-gather bank spread)
#define FS    68    // s_f row stride
#define UPQN  6032  // max(2*29*92=5336, ni 2320 + nh 3712 = 6032); partials live at +2320

__device__ __forceinline__ float silu_f(float x) {
    float e = __expf(-x);
    return x * __builtin_amdgcn_rcpf(1.0f + e);
}

__global__ void k_init(const int* __restrict__ tokens,
                       const float* __restrict__ temb,
                       const float* __restrict__ pemb,
                       float* __restrict__ feats) {
    int o = blockIdx.x * 256 + threadIdx.x;
    if (o >= Bq * Nn * DIMq) return;
    int d = o & (DIMq - 1);
    int bn = o >> 6;
    int n = bn % Nn;
    int t = tokens[bn];
    feats[o] = temb[t * DIMq + d] + pemb[n * DIMq + d];
}

// launch_bounds(512,4): 4 waves/EU -> 16 waves/CU (2 blocks), VGPR cap 128.
// (512,8) forced VGPR<=64 -> massive scratch spill (round-6 regression: 1.8GB FETCH/dispatch).
__global__ __launch_bounds__(512, 4)
void k_layer(const float* __restrict__ feats_in, const float* __restrict__ coors_in,
             float* __restrict__ feats_out, float* __restrict__ coors_out,
             const float* __restrict__ ew1, const float* __restrict__ eb1,
             const float* __restrict__ ew2, const float* __restrict__ eb2,
             const float* __restrict__ cw1, const float* __restrict__ cb1,
             const float* __restrict__ cw2, const float* __restrict__ cb2,
             const float* __restrict__ csc,
             const float* __restrict__ lng, const float* __restrict__ lnb,
             const float* __restrict__ nw1, const float* __restrict__ nb1,
             const float* __restrict__ nw2, const float* __restrict__ nb2,
             int layer) {
    ew1 += (size_t)layer * EIN * EH;   eb1 += layer * EH;
    ew2 += (size_t)layer * EH * MD;    eb2 += layer * MD;
    cw1 += (size_t)layer * MD * CHID;  cb1 += layer * CHID;
    cw2 += layer * CHID;               cb2 += layer;
    lng += layer * DIMq;               lnb += layer * DIMq;
    nw1 += (size_t)layer * NIN * NHID; nb1 += layer * NHID;
    nw2 += (size_t)layer * NHID * DIMq; nb2 += layer * DIMq;
    const float cscale = csc[layer];

    __shared__ float uPQ[UPQN];            // P rows [0..28], Q rows [29..57] per pass; later ni/nh
    __shared__ float s_f[Nn][FS];
    __shared__ float s_c[Nn][3];
    __shared__ int   s_idx[Nn][Kq];
    __shared__ float s_dk[Nn][Kq];
    __shared__ union RegB {                // d2 dead after kNN -> cw/mi
        float d2[Nn][Nn];
        struct { float cw[232]; float mi[Nn][MD]; } e;
    } ub;
    float* s_ni   = uPQ;                   // [Nn][NIN]
    float* s_nh   = uPQ + Nn * NIN;        // [Nn][NHID]
    float* s_part = uPQ + Nn * NIN;        // [232][MD] m-partials (PQ dead by then)

    const int b = blockIdx.x;
    const int tid = threadIdx.x;
    const int half = tid >> 8;             // wave-group half (wave-uniform)
    const int eh = tid & 255;

    // ---- stage feats + coords ----
    const float* fb = feats_in + (size_t)b * Nn * DIMq;
    for (int o = tid; o < Nn * DIMq; o += 512) s_f[o >> 6][o & 63] = fb[o];
    if (tid < Nn * 3) s_c[0][tid] = coors_in[(size_t)b * Nn * 3 + tid];
    __syncthreads();

    // ---- all-pairs squared distances (exact rounding: kNN-critical) ----
    for (int o = tid; o < Nn * Nn; o += 512) {
        int i = o / Nn, j = o % Nn;
        float dx = __fsub_rn(s_c[i][0], s_c[j][0]);
        float dy = __fsub_rn(s_c[i][1], s_c[j][1]);
        float dz = __fsub_rn(s_c[i][2], s_c[j][2]);
        ub.d2[i][j] = __fadd_rn(__fadd_rn(__fmul_rn(dx, dx), __fmul_rn(dy, dy)),
                                __fmul_rn(dz, dz));
    }
    __syncthreads();

    // ---- parallel stable K-nearest: 8 lanes per node (tie: dist2, then index) ----
    if (tid < Nn * Kq) {
        const int g = tid >> 3, l = tid & 7;
        unsigned chosen = 0;
        for (int r = 0; r < Kq; ++r) {
            float bv = 3.4e38f; int bj = 64;
            for (int j = l; j < Nn; j += 8) {
                if ((chosen >> j) & 1u) continue;
                float v = ub.d2[g][j];
                if (v < bv) { bv = v; bj = j; }
            }
            #pragma unroll
            for (int off = 1; off < 8; off <<= 1) {
                float ov = __shfl_xor(bv, off);
                int   oj = __shfl_xor(bj, off);
                if (ov < bv || (ov == bv && oj < bj)) { bv = ov; bj = oj; }
            }
            chosen |= 1u << bj;
            if (l == 0) { s_idx[g][r] = bj; s_dk[g][r] = bv; }
        }
    }
    __syncthreads();

    // ---- edge state: both halves cover all 232 edges, split by c-range ----
    const int e   = (eh < 232) ? eh : 231;
    const int n_e = e >> 3;
    const int k_e = e & 7;
    const int jj  = s_idx[n_e][k_e];
    const float dd = s_dk[n_e][k_e];
    float m[MD];
    #pragma unroll
    for (int q = 0; q < MD; ++q) m[q] = 0.f;

#define ACC_COL(Pv, Qv, CG) do {                                  \
        float pre = (Pv) + (Qv) + dd * wdrow[CG];                 \
        float h = silu_f(pre);                                    \
        const float* w2r = ew2 + (size_t)(CG) * MD;               \
        _Pragma("unroll")                                         \
        for (int q = 0; q < MD; ++q) m[q] = fmaf(h, w2r[q], m[q]);\
    } while (0)

    // ---- three c-passes: P/Q panels -> per-edge streamed accumulation ----
    for (int pass = 0; pass < NPASS; ++pass) {
        const int c0 = pass * PCOLS;

        // P/Q: 344 tasks = 86 cols x {P,Q} x {rows 0-14, 15-28}
        if (tid < 4 * PCOLS) {
            const int cl = tid >> 2, r = tid & 3;
            const bool isP = r < 2;
            const bool full15 = (r & 1) == 0;
            const int n0 = (r & 1) * 15;
            const int cg = c0 + cl;
            const float* wcol = ew1 + (isP ? 0 : 64) * EH + cg;
            float init = isP ? eb1[cg] : 0.f;
            float acc[15];
            #pragma unroll
            for (int u = 0; u < 15; ++u) acc[u] = init;
            #pragma unroll 2
            for (int ig = 0; ig < 16; ++ig) {
                float w0 = wcol[(4 * ig + 0) * EH], w1 = wcol[(4 * ig + 1) * EH];
                float w2v = wcol[(4 * ig + 2) * EH], w3 = wcol[(4 * ig + 3) * EH];
                #pragma unroll
                for (int u = 0; u < 14; ++u) {
                    float4 f4 = *(const float4*)&s_f[n0 + u][4 * ig];
                    acc[u] = fmaf(f4.x, w0, acc[u]);
                    acc[u] = fmaf(f4.y, w1, acc[u]);
                    acc[u] = fmaf(f4.z, w2v, acc[u]);
                    acc[u] = fmaf(f4.w, w3, acc[u]);
                }
                if (full15) {
                    float4 f4 = *(const float4*)&s_f[14][4 * ig];
                    acc[14] = fmaf(f4.x, w0, acc[14]);
                    acc[14] = fmaf(f4.y, w1, acc[14]);
                    acc[14] = fmaf(f4.z, w2v, acc[14]);
                    acc[14] = fmaf(f4.w, w3, acc[14]);
                }
            }
            const int rbase = (isP ? 0 : Nn) + n0;
            #pragma unroll
            for (int u = 0; u < 14; ++u) uPQ[(rbase + u) * PQS + cl] = acc[u];
            if (full15) uPQ[(rbase + 14) * PQS + cl] = acc[14];
        }
        __syncthreads();

        // edge accumulation: half0 -> quads [0,44), half1 -> [44,84) + cols 84,85
        {
            const float* Prow = uPQ + n_e * PQS;
            const float* Qrow = uPQ + (Nn + jj) * PQS;
            const float* wdrow = ew1 + 128 * EH;
            const int cb = half ? 44 : 0;
            const int nq = half ? 10 : 11;
            for (int t = 0; t < nq; ++t) {
                const int cl = cb + 4 * t;
                float4 P4 = *(const float4*)(Prow + cl);
                float4 Q4 = *(const float4*)(Qrow + cl);
                const int cg = c0 + cl;
                ACC_COL(P4.x, Q4.x, cg);
                ACC_COL(P4.y, Q4.y, cg + 1);
                ACC_COL(P4.z, Q4.z, cg + 2);
                ACC_COL(P4.w, Q4.w, cg + 3);
            }
            if (half) {
                ACC_COL(Prow[84], Qrow[84], c0 + 84);
                ACC_COL(Prow[85], Qrow[85], c0 + 85);
            }
        }
        __syncthreads();
    }
#undef ACC_COL

    // ---- m-combine via LDS (PQ panels now dead) ----
    if (half == 1 && eh < 232) {
        float4* pp = (float4*)(s_part + e * MD);
        pp[0] = make_float4(m[0], m[1], m[2], m[3]);
        pp[1] = make_float4(m[4], m[5], m[6], m[7]);
        pp[2] = make_float4(m[8], m[9], m[10], m[11]);
        pp[3] = make_float4(m[12], m[13], m[14], m[15]);
    }
    __syncthreads();

    if (half == 0) {
        // finish edges: combine, silu, coor MLP, cw + mi pool
        const float4* pp = (const float4*)(s_part + e * MD);
        float4 p0 = pp[0], p1 = pp[1], p2 = pp[2], p3 = pp[3];
        m[0] += p0.x; m[1] += p0.y; m[2]  += p0.z; m[3]  += p0.w;
        m[4] += p1.x; m[5] += p1.y; m[6]  += p1.z; m[7]  += p1.w;
        m[8] += p2.x; m[9] += p2.y; m[10] += p2.z; m[11] += p2.w;
        m[12] += p3.x; m[13] += p3.y; m[14] += p3.z; m[15] += p3.w;
        #pragma unroll
        for (int q = 0; q < MD; ++q) m[q] = silu_f(eb2[q] + m[q]);

        float cwacc = cb2[0];
        #pragma unroll
        for (int ch = 0; ch < 4; ++ch) {
            float hh[16];
            const float* cb1c = cb1 + 16 * ch;
            #pragma unroll
            for (int q = 0; q < 16; ++q) hh[q] = cb1c[q];
            #pragma unroll
            for (int i = 0; i < MD; ++i) {
                const float* wr = cw1 + i * CHID + 16 * ch;   // uniform -> s_load
                #pragma unroll
                for (int q = 0; q < 16; ++q) hh[q] = fmaf(m[i], wr[q], hh[q]);
            }
            const float* cw2c = cw2 + 16 * ch;
            #pragma unroll
            for (int q = 0; q < 16; ++q) cwacc = fmaf(silu_f(hh[q]), cw2c[q], cwacc);
        }
        cwacc = fminf(fmaxf(cwacc, -2.f), 2.f);
        if (eh < 232) ub.e.cw[e] = cwacc;

        #pragma unroll
        for (int q = 0; q < MD; ++q) {
            float v = m[q];
            v += __shfl_xor(v, 1);
            v += __shfl_xor(v, 2);
            v += __shfl_xor(v, 4);
            if (k_e == 0 && eh < 232) ub.e.mi[n_e][q] = v;
        }
    } else if (eh < Nn * Kq) {
        // concurrent LayerNorm on half1 (PQ region [0,2320) now reusable as ni)
        const int g = eh >> 3, l = eh & 7;
        const float* fr = s_f[g];
        float4 a = *(const float4*)&fr[8 * l];
        float4 b4 = *(const float4*)&fr[8 * l + 4];
        float ps = ((a.x + a.y) + (a.z + a.w)) + ((b4.x + b4.y) + (b4.z + b4.w));
        ps += __shfl_xor(ps, 1); ps += __shfl_xor(ps, 2); ps += __shfl_xor(ps, 4);
        float mu = ps * (1.0f / 64.0f);
        float t0, pv = 0.f;
        t0 = a.x - mu;  pv = fmaf(t0, t0, pv);  t0 = a.y - mu;  pv = fmaf(t0, t0, pv);
        t0 = a.z - mu;  pv = fmaf(t0, t0, pv);  t0 = a.w - mu;  pv = fmaf(t0, t0, pv);
        t0 = b4.x - mu; pv = fmaf(t0, t0, pv);  t0 = b4.y - mu; pv = fmaf(t0, t0, pv);
        t0 = b4.z - mu; pv = fmaf(t0, t0, pv);  t0 = b4.w - mu; pv = fmaf(t0, t0, pv);
        pv += __shfl_xor(pv, 1); pv += __shfl_xor(pv, 2); pv += __shfl_xor(pv, 4);
        float rs = rsqrtf(pv * (1.0f / 64.0f) + 1e-5f);
        #pragma unroll
        for (int u = 0; u < 8; ++u) {
            int d = 8 * l + u;
            s_ni[g * NIN + d] = (fr[d] - mu) * rs * lng[d] + lnb[d];
        }
    }
    __syncthreads();

    // ---- mi copy (lanes 0..447 + wrap) and coords update (wave 7) ----
    if (tid < 448) {
        s_ni[(tid >> 4) * NIN + DIMq + (tid & 15)] = ub.e.mi[tid >> 4][tid & 15];
        if (tid < 16) s_ni[28 * NIN + DIMq + tid] = ub.e.mi[28][tid];
    } else {
        for (int t2 = tid - 448; t2 < Nn * 3; t2 += 64) {
            int n2 = t2 / 3, cix = t2 % 3;
            float acc2 = 0.f;
            for (int k2 = 0; k2 < Kq; ++k2) {
                int j2 = s_idx[n2][k2];
                float nrm = sqrtf(s_dk[n2][k2]);
                float rel = __fsub_rn(s_c[n2][cix], s_c[j2][cix]);
                float rn = rel / fmaxf(nrm, 1e-8f) * cscale;
                acc2 = fmaf(ub.e.cw[n2 * Kq + k2], rn, acc2);
            }
            coors_out[((size_t)b * Nn + n2) * 3 + cix] = s_c[n2][cix] + acc2;
        }
    }
    __syncthreads();

    // ---- node MLP hidden ----
    for (int o = tid; o < Nn * NHID; o += 512) {
        int n2 = o >> 7, c = o & 127;
        float acc = nb1[c];
        const float* nir = s_ni + n2 * NIN;
        const float* w = nw1 + c;
        #pragma unroll 4
        for (int ig = 0; ig < 20; ++ig) {
            float4 f4 = *(const float4*)(nir + 4 * ig);
            acc = fmaf(f4.x, w[(4 * ig + 0) * NHID], acc);
            acc = fmaf(f4.y, w[(4 * ig + 1) * NHID], acc);
            acc = fmaf(f4.z, w[(4 * ig + 2) * NHID], acc);
            acc = fmaf(f4.w, w[(4 * ig + 3) * NHID], acc);
        }
        s_nh[n2 * NHID + c] = silu_f(acc);
    }
    __syncthreads();

    // ---- node MLP out + residual ----
    for (int o = tid; o < Nn * DIMq; o += 512) {
        int n2 = o >> 6, c = o & 63;
        float acc = nb2[c];
        const float* nhr = s_nh + n2 * NHID;
        const float* w = nw2 + c;
        #pragma unroll 4
        for (int ig = 0; ig < 32; ++ig) {
            float4 f4 = *(const float4*)(nhr + 4 * ig);
            acc = fmaf(f4.x, w[(4 * ig + 0) * DIMq], acc);
            acc = fmaf(f4.y, w[(4 * ig + 1) * DIMq], acc);
            acc = fmaf(f4.z, w[(4 * ig + 2) * DIMq], acc);
            acc = fmaf(f4.w, w[(4 * ig + 3) * DIMq], acc);
        }
        feats_out[((size_t)b * Nn + n2) * DIMq + c] = acc + s_f[n2][c];
    }
}

__global__ __launch_bounds__(64)
void k_read(const float* __restrict__ feats,
            const float* __restrict__ rw1, const float* __restrict__ rb1,
            const float* __restrict__ rw2, const float* __restrict__ rb2,
            float* __restrict__ out) {
    __shared__ float s_mol[DIMq];
    const int b = blockIdx.x, t = threadIdx.x;
    float acc = 0.f;
    for (int n = 0; n < Nn; ++n) acc += feats[((size_t)b * Nn + n) * DIMq + t];
    s_mol[t] = acc / 29.0f;
    __syncthreads();
    float a2 = rb1[t];
    for (int i = 0; i < DIMq; ++i) a2 = fmaf(s_mol[i], rw1[i * DIMq + t], a2);
    float part = silu_f(a2) * rw2[t];
    #pragma unroll
    for (int off = 32; off > 0; off >>= 1) part += __shfl_down(part, off);
    if (t == 0) out[b] = part + rb2[0];
}

extern "C" void kernel_launch(void* const* d_in, const int* in_sizes, int n_in,
                              void* d_out, int out_size, void* d_ws, size_t ws_size,
                              hipStream_t stream) {
    const int*   tokens = (const int*)d_in[0];
    const float* coords = (const float*)d_in[1];
    // d_in[2] = mask : all-True in this problem
    const float* temb = (const float*)d_in[3];
    const float* pemb = (const float*)d_in[4];
    const float* ew1 = (const float*)d_in[5];
    const float* eb1 = (const float*)d_in[6];
    const float* ew2 = (const float*)d_in[7];
    const float* eb2 = (const float*)d_in[8];
    const float* cw1 = (const float*)d_in[9];
    const float* cb1 = (const float*)d_in[10];
    const float* cw2 = (const float*)d_in[11];
    const float* cb2 = (const float*)d_in[12];
    const float* csc = (const float*)d_in[13];
    const float* lng = (const float*)d_in[14];
    const float* lnb = (const float*)d_in[15];
    const float* nw1 = (const float*)d_in[16];
    const float* nb1 = (const float*)d_in[17];
    const float* nw2 = (const float*)d_in[18];
    const float* nb2 = (const float*)d_in[19];
    const float* rw1 = (const float*)d_in[20];
    const float* rb1 = (const float*)d_in[21];
    const float* rw2 = (const float*)d_in[22];
    const float* rb2 = (const float*)d_in[23];

    float* fA = (float*)d_ws;
    float* fB = fA + (size_t)Bq * Nn * DIMq;
    float* cA = fB + (size_t)Bq * Nn * DIMq;
    float* cB = cA + (size_t)Bq * Nn * 3;

    k_init<<<(Bq * Nn * DIMq + 255) / 256, 256, 0, stream>>>(tokens, temb, pemb, fA);

    const float* fin = fA;
    const float* cin = coords;
    float* fbufs[2] = {fB, fA};
    float* cbufs[2] = {cA, cB};
    for (int l = 0; l < DEPTHq; ++l) {
        float* fout = fbufs[l & 1];
        float* cout = cbufs[l & 1];
        k_layer<<<Bq, 512, 0, stream>>>(fin, cin, fout, cout,
                                        ew1, eb1, ew2, eb2,
                                        cw1, cb1, cw2, cb2, csc,
                                        lng, lnb, nw1, nb1, nw2, nb2, l);
        fin = fout;
        cin = cout;
    }

    k_read<<<Bq, 64, 0, stream>>>(fin, rw1, rb1, rw2, rb2, (float*)d_out);
}

// Round 8
// 616.527 us; speedup vs baseline: 8.2763x; 1.6859x over previous
//
#include <hip/hip_runtime.h>
#include <math.h>

#define Bq    1024
#define Nn    29
#define DIMq  64
#define Kq    8
#define MD    16
#define EIN   129
#define EH    258   // 2*EIN
#define CHID  64    // 4*MD
#define NIN   80    // DIM+MD
#define NHID  128   // 2*DIM
#define DEPTHq 4
#define NPASS 4
#define PQS   68    // P/Q LDS row stride (64+4)
#define FS    68    // s_f row stride
#define UPQN  6032  // max(2*29*68=3944, ni 2320 + nh 3712 = 6032)

__device__ __forceinline__ float silu_f(float x) {
    float e = __expf(-x);
    return x * __builtin_amdgcn_rcpf(1.0f + e);
}

// Whole-network fusion: one block = one molecule through init + 4 EGNN layers +
// readout. feats/coors stay in LDS across layers (no global round-trips, no
// inter-layer grid drains). 256 threads, 4 blocks/CU (R7 showed 512-thread
// blocks over-couple waves at barriers; R6 showed (·,8) bounds force spill).
__global__ __launch_bounds__(256, 4)
void k_egnn(const int* __restrict__ tokens, const float* __restrict__ coords,
            const float* __restrict__ temb, const float* __restrict__ pemb,
            const float* __restrict__ ew1, const float* __restrict__ eb1,
            const float* __restrict__ ew2, const float* __restrict__ eb2,
            const float* __restrict__ cw1, const float* __restrict__ cb1,
            const float* __restrict__ cw2, const float* __restrict__ cb2,
            const float* __restrict__ csc,
            const float* __restrict__ lng, const float* __restrict__ lnb,
            const float* __restrict__ nw1, const float* __restrict__ nb1,
            const float* __restrict__ nw2, const float* __restrict__ nb2,
            const float* __restrict__ rw1, const float* __restrict__ rb1,
            const float* __restrict__ rw2, const float* __restrict__ rb2,
            float* __restrict__ out) {
    __shared__ float uPQ[UPQN];            // P/Q panels per pass; later ni/nh; finally mol
    __shared__ float s_f[Nn][FS];          // persistent feats (updated in place per layer)
    __shared__ float s_c[2][Nn][3];        // coords, double-buffered per layer
    __shared__ int   s_idx[Nn][Kq];
    __shared__ float s_dk[Nn][Kq];
    __shared__ union RegB {                // d2 dead after kNN -> cw/mi
        float d2[Nn][Nn];
        struct { float cw[232]; float mi[Nn][MD]; } e;
    } ub;
    float* s_ni = uPQ;                     // [Nn][NIN]
    float* s_nh = uPQ + Nn * NIN;          // [Nn][NHID]

    const int b = blockIdx.x;
    const int tid = threadIdx.x;

    // ---- init: feats = token_emb[tokens] + pos_emb ; stage coords ----
    for (int o = tid; o < Nn * DIMq; o += 256) {
        int n = o >> 6, d = o & 63;
        s_f[n][d] = temb[tokens[b * Nn + n] * DIMq + d] + pemb[o];
    }
    if (tid < Nn * 3) s_c[0][0][tid] = coords[(size_t)b * Nn * 3 + tid];
    int cp = 0;

    for (int l = 0; l < DEPTHq; ++l) {
        const float* ew1l = ew1 + (size_t)l * EIN * EH;  const float* eb1l = eb1 + l * EH;
        const float* ew2l = ew2 + (size_t)l * EH * MD;   const float* eb2l = eb2 + l * MD;
        const float* cw1l = cw1 + (size_t)l * MD * CHID; const float* cb1l = cb1 + l * CHID;
        const float* cw2l = cw2 + l * CHID;              const float* cb2l = cb2 + l;
        const float* lngl = lng + l * DIMq;              const float* lnbl = lnb + l * DIMq;
        const float* nw1l = nw1 + (size_t)l * NIN * NHID;  const float* nb1l = nb1 + l * NHID;
        const float* nw2l = nw2 + (size_t)l * NHID * DIMq; const float* nb2l = nb2 + l * DIMq;
        const float cscale = csc[l];

        __syncthreads();   // s_f/s_c/uPQ stable before this layer reads them

        // ---- all-pairs squared distances (exact rounding: kNN-critical) ----
        for (int o = tid; o < Nn * Nn; o += 256) {
            int i = o / Nn, j = o % Nn;
            float dx = __fsub_rn(s_c[cp][i][0], s_c[cp][j][0]);
            float dy = __fsub_rn(s_c[cp][i][1], s_c[cp][j][1]);
            float dz = __fsub_rn(s_c[cp][i][2], s_c[cp][j][2]);
            ub.d2[i][j] = __fadd_rn(__fadd_rn(__fmul_rn(dx, dx), __fmul_rn(dy, dy)),
                                    __fmul_rn(dz, dz));
        }
        __syncthreads();

        // ---- parallel stable K-nearest: 8 lanes per node (tie: dist2, then index) ----
        if (tid < Nn * Kq) {
            const int g = tid >> 3, lk = tid & 7;
            unsigned chosen = 0;
            for (int r = 0; r < Kq; ++r) {
                float bv = 3.4e38f; int bj = 64;
                for (int j = lk; j < Nn; j += 8) {
                    if ((chosen >> j) & 1u) continue;
                    float v = ub.d2[g][j];
                    if (v < bv) { bv = v; bj = j; }
                }
                #pragma unroll
                for (int off = 1; off < 8; off <<= 1) {
                    float ov = __shfl_xor(bv, off);
                    int   oj = __shfl_xor(bj, off);
                    if (ov < bv || (ov == bv && oj < bj)) { bv = ov; bj = oj; }
                }
                chosen |= 1u << bj;
                if (lk == 0) { s_idx[g][r] = bj; s_dk[g][r] = bv; }
            }
        }
        __syncthreads();

        // ---- edge state (uniform flow; writes masked) ----
        const int e   = (tid < 232) ? tid : 231;
        const int n_e = e >> 3;
        const int k_e = e & 7;
        const int jj  = s_idx[n_e][k_e];
        const float dd = s_dk[n_e][k_e];
        float m[MD];
        #pragma unroll
        for (int q = 0; q < MD; ++q) m[q] = 0.f;

#define ACC_COL(Pv, Qv, CG) do {                                  \
        float pre = (Pv) + (Qv) + dd * wdrow[CG];                 \
        float h = silu_f(pre);                                    \
        const float* w2r = ew2l + (size_t)(CG) * MD;              \
        _Pragma("unroll")                                         \
        for (int q = 0; q < MD; ++q) m[q] = fmaf(h, w2r[q], m[q]);\
    } while (0)

        // ---- four c-passes (64,64,64,66 cols): P/Q panels -> edge accumulation ----
        for (int pass = 0; pass < NPASS; ++pass) {
            const int c0 = pass * 64;
            const int cols = (pass == 3) ? 66 : 64;

            // P/Q: 4*cols tasks = cols x {P,Q} x {rows 0-14, 15-28}; 256 tasks/pass
            for (int it = 0; it < 2; ++it) {
                const int t = tid + it * 256;
                if (t >= 4 * cols) break;
                const int cl = t >> 2, r = t & 3;
                const bool isP = r < 2;
                const bool full15 = (r & 1) == 0;
                const int n0 = (r & 1) * 15;
                const int cg = c0 + cl;
                const float* wcol = ew1l + (isP ? 0 : 64) * EH + cg;
                float init = isP ? eb1l[cg] : 0.f;
                float acc[15];
                #pragma unroll
                for (int u = 0; u < 15; ++u) acc[u] = init;
                #pragma unroll 2
                for (int ig = 0; ig < 16; ++ig) {
                    float w0 = wcol[(4 * ig + 0) * EH], w1 = wcol[(4 * ig + 1) * EH];
                    float w2v = wcol[(4 * ig + 2) * EH], w3 = wcol[(4 * ig + 3) * EH];
                    #pragma unroll
                    for (int u = 0; u < 14; ++u) {
                        float4 f4 = *(const float4*)&s_f[n0 + u][4 * ig];
                        acc[u] = fmaf(f4.x, w0, acc[u]);
                        acc[u] = fmaf(f4.y, w1, acc[u]);
                        acc[u] = fmaf(f4.z, w2v, acc[u]);
                        acc[u] = fmaf(f4.w, w3, acc[u]);
                    }
                    if (full15) {
                        float4 f4 = *(const float4*)&s_f[14][4 * ig];
                        acc[14] = fmaf(f4.x, w0, acc[14]);
                        acc[14] = fmaf(f4.y, w1, acc[14]);
                        acc[14] = fmaf(f4.z, w2v, acc[14]);
                        acc[14] = fmaf(f4.w, w3, acc[14]);
                    }
                }
                const int rbase = (isP ? 0 : Nn) + n0;
                #pragma unroll
                for (int u = 0; u < 14; ++u) uPQ[(rbase + u) * PQS + cl] = acc[u];
                if (full15) uPQ[(rbase + 14) * PQS + cl] = acc[14];
            }
            __syncthreads();

            // edge accumulation over this pass (uniform loop; scalar weight reads)
            {
                const float* Prow = uPQ + n_e * PQS;
                const float* Qrow = uPQ + (Nn + jj) * PQS;
                const float* wdrow = ew1l + 128 * EH;
                for (int qd = 0; qd < 16; ++qd) {
                    const int cl = 4 * qd;
                    float4 P4 = *(const float4*)(Prow + cl);
                    float4 Q4 = *(const float4*)(Qrow + cl);
                    const int cg = c0 + cl;
                    ACC_COL(P4.x, Q4.x, cg);
                    ACC_COL(P4.y, Q4.y, cg + 1);
                    ACC_COL(P4.z, Q4.z, cg + 2);
                    ACC_COL(P4.w, Q4.w, cg + 3);
                }
                if (pass == 3) {
                    ACC_COL(Prow[64], Qrow[64], c0 + 64);
                    ACC_COL(Prow[65], Qrow[65], c0 + 65);
                }
            }
            __syncthreads();
        }
#undef ACC_COL

        // ---- finish edge: m silu, coor MLP, cw + mi pool ----
        {
            #pragma unroll
            for (int q = 0; q < MD; ++q) m[q] = silu_f(eb2l[q] + m[q]);

            float cwacc = cb2l[0];
            #pragma unroll
            for (int ch = 0; ch < 4; ++ch) {
                float hh[16];
                const float* cb1c = cb1l + 16 * ch;
                #pragma unroll
                for (int q = 0; q < 16; ++q) hh[q] = cb1c[q];
                #pragma unroll
                for (int i = 0; i < MD; ++i) {
                    const float* wr = cw1l + i * CHID + 16 * ch;   // uniform -> s_load
                    #pragma unroll
                    for (int q = 0; q < 16; ++q) hh[q] = fmaf(m[i], wr[q], hh[q]);
                }
                const float* cw2c = cw2l + 16 * ch;
                #pragma unroll
                for (int q = 0; q < 16; ++q) cwacc = fmaf(silu_f(hh[q]), cw2c[q], cwacc);
            }
            cwacc = fminf(fmaxf(cwacc, -2.f), 2.f);
            if (tid < 232) ub.e.cw[e] = cwacc;

            #pragma unroll
            for (int q = 0; q < MD; ++q) {
                float v = m[q];
                v += __shfl_xor(v, 1);
                v += __shfl_xor(v, 2);
                v += __shfl_xor(v, 4);
                if (k_e == 0 && tid < 232) ub.e.mi[n_e][q] = v;
            }
        }
        __syncthreads();

        // ---- coords update (87 lanes -> s_c[cp^1]) + LayerNorm/ni build (232 lanes) ----
        if (tid < Nn * 3) {
            int n2 = tid / 3, cix = tid % 3;
            float acc2 = 0.f;
            for (int k2 = 0; k2 < Kq; ++k2) {
                int j2 = s_idx[n2][k2];
                float nrm = sqrtf(s_dk[n2][k2]);
                float rel = __fsub_rn(s_c[cp][n2][cix], s_c[cp][j2][cix]);
                float rn = rel / fmaxf(nrm, 1e-8f) * cscale;
                acc2 = fmaf(ub.e.cw[n2 * Kq + k2], rn, acc2);
            }
            s_c[cp ^ 1][n2][cix] = s_c[cp][n2][cix] + acc2;   // write other buffer: no race
        }
        if (tid < Nn * Kq) {
            const int g = tid >> 3, lk = tid & 7;
            const float* fr = s_f[g];
            float4 a = *(const float4*)&fr[8 * lk];
            float4 b4 = *(const float4*)&fr[8 * lk + 4];
            float ps = ((a.x + a.y) + (a.z + a.w)) + ((b4.x + b4.y) + (b4.z + b4.w));
            ps += __shfl_xor(ps, 1); ps += __shfl_xor(ps, 2); ps += __shfl_xor(ps, 4);
            float mu = ps * (1.0f / 64.0f);
            float t0, pv = 0.f;
            t0 = a.x - mu;  pv = fmaf(t0, t0, pv);  t0 = a.y - mu;  pv = fmaf(t0, t0, pv);
            t0 = a.z - mu;  pv = fmaf(t0, t0, pv);  t0 = a.w - mu;  pv = fmaf(t0, t0, pv);
            t0 = b4.x - mu; pv = fmaf(t0, t0, pv);  t0 = b4.y - mu; pv = fmaf(t0, t0, pv);
            t0 = b4.z - mu; pv = fmaf(t0, t0, pv);  t0 = b4.w - mu; pv = fmaf(t0, t0, pv);
            pv += __shfl_xor(pv, 1); pv += __shfl_xor(pv, 2); pv += __shfl_xor(pv, 4);
            float rs = rsqrtf(pv * (1.0f / 64.0f) + 1e-5f);
            #pragma unroll
            for (int u = 0; u < 8; ++u) {
                int d = 8 * lk + u;
                s_ni[g * NIN + d] = (fr[d] - mu) * rs * lngl[d] + lnbl[d];
            }
            if (lk < 2) {
                #pragma unroll
                for (int u = 0; u < 8; ++u)
                    s_ni[g * NIN + DIMq + 8 * lk + u] = ub.e.mi[g][8 * lk + u];
            }
        }
        __syncthreads();

        // ---- node MLP hidden ----
        for (int o = tid; o < Nn * NHID; o += 256) {
            int n2 = o >> 7, c = o & 127;
            float acc = nb1l[c];
            const float* nir = s_ni + n2 * NIN;
            const float* w = nw1l + c;
            #pragma unroll 4
            for (int ig = 0; ig < 20; ++ig) {
                float4 f4 = *(const float4*)(nir + 4 * ig);
                acc = fmaf(f4.x, w[(4 * ig + 0) * NHID], acc);
                acc = fmaf(f4.y, w[(4 * ig + 1) * NHID], acc);
                acc = fmaf(f4.z, w[(4 * ig + 2) * NHID], acc);
                acc = fmaf(f4.w, w[(4 * ig + 3) * NHID], acc);
            }
            s_nh[n2 * NHID + c] = silu_f(acc);
        }
        __syncthreads();

        // ---- node MLP out + residual: update s_f in place (owner lane) ----
        for (int o = tid; o < Nn * DIMq; o += 256) {
            int n2 = o >> 6, c = o & 63;
            float acc = nb2l[c];
            const float* nhr = s_nh + n2 * NHID;
            const float* w = nw2l + c;
            #pragma unroll 4
            for (int ig = 0; ig < 32; ++ig) {
                float4 f4 = *(const float4*)(nhr + 4 * ig);
                acc = fmaf(f4.x, w[(4 * ig + 0) * DIMq], acc);
                acc = fmaf(f4.y, w[(4 * ig + 1) * DIMq], acc);
                acc = fmaf(f4.z, w[(4 * ig + 2) * DIMq], acc);
                acc = fmaf(f4.w, w[(4 * ig + 3) * DIMq], acc);
            }
            s_f[n2][c] = acc + s_f[n2][c];
        }
        cp ^= 1;
    }
    __syncthreads();

    // ---- fused readout: mol mean -> silu(mol@rw1+rb1)@rw2 + rb2 ----
    float* s_mol = uPQ;
    if (tid < DIMq) {
        float acc = 0.f;
        for (int n = 0; n < Nn; ++n) acc += s_f[n][tid];
        s_mol[tid] = acc / 29.0f;
    }
    __syncthreads();
    if (tid < DIMq) {
        float a2 = rb1[tid];
        for (int i = 0; i < DIMq; ++i) a2 = fmaf(s_mol[i], rw1[i * DIMq + tid], a2);
        float part = silu_f(a2) * rw2[tid];
        #pragma unroll
        for (int off = 32; off > 0; off >>= 1) part += __shfl_down(part, off);
        if (tid == 0) out[b] = part + rb2[0];
    }
}

extern "C" void kernel_launch(void* const* d_in, const int* in_sizes, int n_in,
                              void* d_out, int out_size, void* d_ws, size_t ws_size,
                              hipStream_t stream) {
    const int*   tokens = (const int*)d_in[0];
    const float* coords = (const float*)d_in[1];
    // d_in[2] = mask : all-True in this problem
    const float* temb = (const float*)d_in[3];
    const float* pemb = (const float*)d_in[4];
    const float* ew1 = (const float*)d_in[5];
    const float* eb1 = (const float*)d_in[6];
    const float* ew2 = (const float*)d_in[7];
    const float* eb2 = (const float*)d_in[8];
    const float* cw1 = (const float*)d_in[9];
    const float* cb1 = (const float*)d_in[10];
    const float* cw2 = (const float*)d_in[11];
    const float* cb2 = (const float*)d_in[12];
    const float* csc = (const float*)d_in[13];
    const float* lng = (const float*)d_in[14];
    const float* lnb = (const float*)d_in[15];
    const float* nw1 = (const float*)d_in[16];
    const float* nb1 = (const float*)d_in[17];
    const float* nw2 = (const float*)d_in[18];
    const float* nb2 = (const float*)d_in[19];
    const float* rw1 = (const float*)d_in[20];
    const float* rb1 = (const float*)d_in[21];
    const float* rw2 = (const float*)d_in[22];
    const float* rb2 = (const float*)d_in[23];

    k_egnn<<<Bq, 256, 0, stream>>>(tokens, coords, temb, pemb,
                                   ew1, eb1, ew2, eb2,
                                   cw1, cb1, cw2, cb2, csc,
                                   lng, lnb, nw1, nb1, nw2, nb2,
                                   rw1, rb1, rw2, rb2, (float*)d_out);
}